// Round 14
// baseline (301.755 us; speedup 1.0000x reference)
//
#include <hip/hip_runtime.h>
#include <hip/hip_bf16.h>
#include <math.h>

namespace {

constexpr int C = 128;  // channels
constexpr int K = 32;   // max degree
constexpr int NB = 8;   // node-range buckets == XCD count

typedef float float4v __attribute__((ext_vector_type(4)));
typedef short short8v __attribute__((ext_vector_type(8)));   // 8 bf16 (4 VGPR)
typedef unsigned short ushort8v __attribute__((ext_vector_type(8)));

__device__ __forceinline__ float bf2f(unsigned short u) {
    return __uint_as_float(((unsigned int)u) << 16);
}
__device__ __forceinline__ unsigned short f2bf(float x) {
    __hip_bfloat16 h = __float2bfloat16(x);
    return *(unsigned short*)&h;
}

// ---------------------------------------------------------------------------
// Kernel 0 (prep): one thread per node.
//  - invs[n] = 1/sqrt(1+#valid)
//  - bucket-sort the node's 32 edge indices by node-range (8 ranges of
//    ~(N+1)/8 rows; -1 maps to zero-row N, range 7) -> sedge[n][32] +
//    per-range counts packed 8x8 bits in offs[n]. Bucketing is a locality
//    heuristic: any consistent assignment is correct.
//  Side jobs: block 0 zeroes h1 row N; blocks 1..128 pre-split W1/W2 into
//  hi/lo bf16 planes (whl) for the split-bf16 MFMA GEMMs.
// ---------------------------------------------------------------------------
__global__ __launch_bounds__(256) void prep_kernel(
    const int* __restrict__ edge, int* __restrict__ sedge,
    unsigned long long* __restrict__ offs, float* __restrict__ invs,
    unsigned int* __restrict__ hz1, const float* __restrict__ W1,
    const float* __restrict__ W2, unsigned short* __restrict__ whl, int N,
    int do_sort) {
    const int bid = blockIdx.x;
    const int t = threadIdx.x;

    if (bid == 0 && t < 64) hz1[(size_t)N * (C / 2) + t] = 0u;
    if (bid >= 1 && bid <= 128) {
        int which = (bid - 1) >> 6;           // 0: W1, 1: W2
        int p = ((bid - 1) & 63) * 256 + t;   // 0..16383
        float w = (which ? W2 : W1)[p];
        unsigned short hb = f2bf(w);
        unsigned short lb = f2bf(w - bf2f(hb));
        unsigned short* dst = whl + (size_t)which * 32768;
        dst[p] = hb;
        dst[16384 + p] = lb;
    }

    const int node = bid * 256 + t;
    if (node >= N) return;

    int j[32];
    const int4* ep = (const int4*)(edge + (size_t)node * K);
#pragma unroll
    for (int q = 0; q < 8; ++q) {
        int4 e = ep[q];
        j[q * 4 + 0] = e.x;
        j[q * 4 + 1] = e.y;
        j[q * 4 + 2] = e.z;
        j[q * 4 + 3] = e.w;
    }
    int valid = 0;
#pragma unroll
    for (int k = 0; k < K; ++k) valid += (j[k] >= 0) ? 1 : 0;
    invs[node] = 1.0f / sqrtf((float)(valid + 1));

    if (!do_sort) return;

    const float binv = 8.0f / (float)(N + 1);
    int b[32];
    unsigned long long cnts = 0;
#pragma unroll
    for (int k = 0; k < K; ++k) {
        int jj = j[k] < 0 ? N : j[k];
        j[k] = jj;
        int bb = (int)((float)jj * binv);
        bb = bb > 7 ? 7 : bb;
        b[k] = bb;
        cnts += 1ull << (8 * bb);
    }
    offs[node] = cnts;

    int* dst = sedge + (size_t)node * K;
    int pos = 0;
#pragma unroll
    for (int bb = 0; bb < NB; ++bb)
#pragma unroll
        for (int k = 0; k < K; ++k)
            if (b[k] == bb) dst[pos++] = j[k];
}

// ---------------------------------------------------------------------------
// Kernel 1: H[n][ch] = bf16( (X[n] . W[ch]) * invs[n] )   (round-11 proven)
// Split-bf16 MFMA GEMM, 3-term (fp32 A): pre-split W planes staged to LDS.
// ---------------------------------------------------------------------------
__global__ __launch_bounds__(256, 2) void gemm_mfma_kernel(
    const float* __restrict__ X, const unsigned short* __restrict__ Wp,
    const float* __restrict__ invs, unsigned short* __restrict__ H, int N) {
    __shared__ unsigned short Whl[2][C][136];

    const int t = threadIdx.x;
    const int n0 = blockIdx.x * 128;

    for (int p = t; p < 2 * C * 16; p += 256) {
        int seg = p >> 11;
        int rem = p & 2047;
        int row = rem >> 4;
        int v8 = (rem & 15) * 8;
        *(ushort8v*)&Whl[seg][row][v8] =
            *(const ushort8v*)(Wp + (size_t)seg * 16384 + row * 128 + v8);
    }
    __syncthreads();

    const int wv = t >> 6;
    const int l = t & 63;
    const int lm = l & 15;
    const int lk = l >> 4;
    const int rbase = n0 + wv * 32;

    int rowA0 = rbase + lm;
    int rowA1 = rbase + 16 + lm;
    rowA0 = rowA0 < N ? rowA0 : N - 1;
    rowA1 = rowA1 < N ? rowA1 : N - 1;
    const float* xp0 = X + (size_t)rowA0 * C;
    const float* xp1 = X + (size_t)rowA1 * C;

    float4v acc[2][8];
#pragma unroll
    for (int rt = 0; rt < 2; ++rt)
#pragma unroll
        for (int ct = 0; ct < 8; ++ct) acc[rt][ct] = {0.f, 0.f, 0.f, 0.f};

#pragma unroll
    for (int ks = 0; ks < 4; ++ks) {
        const int kb = ks * 32 + lk * 8;
        float xr0[8], xr1[8];
        *(float4v*)&xr0[0] = *(const float4v*)(xp0 + kb);
        *(float4v*)&xr0[4] = *(const float4v*)(xp0 + kb + 4);
        *(float4v*)&xr1[0] = *(const float4v*)(xp1 + kb);
        *(float4v*)&xr1[4] = *(const float4v*)(xp1 + kb + 4);
        short8v ah0, al0, ah1, al1;
#pragma unroll
        for (int j = 0; j < 8; ++j) {
            unsigned short h0 = f2bf(xr0[j]);
            unsigned short h1 = f2bf(xr1[j]);
            ah0[j] = (short)h0;
            ah1[j] = (short)h1;
            al0[j] = (short)f2bf(xr0[j] - bf2f(h0));
            al1[j] = (short)f2bf(xr1[j] - bf2f(h1));
        }
#pragma unroll
        for (int ct = 0; ct < 8; ++ct) {
            short8v bh = *(const short8v*)&Whl[0][ct * 16 + lm][kb];
            short8v bl = *(const short8v*)&Whl[1][ct * 16 + lm][kb];
            acc[0][ct] = __builtin_amdgcn_mfma_f32_16x16x32_bf16(ah0, bh,
                                                                 acc[0][ct], 0, 0, 0);
            acc[0][ct] = __builtin_amdgcn_mfma_f32_16x16x32_bf16(al0, bh,
                                                                 acc[0][ct], 0, 0, 0);
            acc[0][ct] = __builtin_amdgcn_mfma_f32_16x16x32_bf16(ah0, bl,
                                                                 acc[0][ct], 0, 0, 0);
            acc[1][ct] = __builtin_amdgcn_mfma_f32_16x16x32_bf16(ah1, bh,
                                                                 acc[1][ct], 0, 0, 0);
            acc[1][ct] = __builtin_amdgcn_mfma_f32_16x16x32_bf16(al1, bh,
                                                                 acc[1][ct], 0, 0, 0);
            acc[1][ct] = __builtin_amdgcn_mfma_f32_16x16x32_bf16(ah1, bl,
                                                                 acc[1][ct], 0, 0, 0);
        }
    }

    float sc[2][4];
#pragma unroll
    for (int rt = 0; rt < 2; ++rt)
#pragma unroll
        for (int q = 0; q < 4; ++q) {
            int r = rbase + rt * 16 + lk * 4 + q;
            sc[rt][q] = invs[r < N ? r : N - 1];
        }
#pragma unroll
    for (int rt = 0; rt < 2; ++rt)
#pragma unroll
        for (int ct = 0; ct < 8; ++ct)
#pragma unroll
            for (int q = 0; q < 4; ++q) {
                int r = rbase + rt * 16 + lk * 4 + q;
                if (r < N)
                    H[(size_t)r * C + ct * 16 + lm] =
                        f2bf(acc[rt][ct][q] * sc[rt][q]);
            }
}

// ---------------------------------------------------------------------------
// Kernel 2 (bucketed gather + ELU): neighbor lists are pre-sorted by node
// range; process ranges pass-by-pass with per-XCD rotation p=(blockIdx&7+pp)&7
// so each XCD streams ONE 3.2 MB range at a time (fits its private 4 MiB L2).
// Round-13 diagnosis: 358 MB beyond-L2 traffic @3.3 TB/s WAS the 108 us; the
// compulsory minimum is 8 XCDs x 25.6 MB = 205 MB. Inner loop unrolled x2 for
// MLP; indices are pre-clamped (-1 -> zero-row N) so loads are unconditional.
// Deterministic: rotation depends only on blockIdx.
// ---------------------------------------------------------------------------
__global__ __launch_bounds__(256) void gather_elu_b_kernel(
    const unsigned short* __restrict__ H, const int* __restrict__ sedge,
    const unsigned long long* __restrict__ offs, const float* __restrict__ invs,
    float* __restrict__ out, int N) {
    __shared__ int idx_s[8][K];
    __shared__ int start_s[8][NB + 1];

    const int t = threadIdx.x;
    const int g = t >> 5;
    const int lane32 = t & 31;
    const int node = blockIdx.x * 8 + g;

    idx_s[g][lane32] = (node < N) ? sedge[(size_t)node * K + lane32] : N;
    if (lane32 == 0) {
        unsigned long long cc = (node < N) ? offs[node] : 0ull;
        int a = 0;
#pragma unroll
        for (int bb = 0; bb < NB; ++bb) {
            start_s[g][bb] = a;
            a += (int)((cc >> (8 * bb)) & 255ull);
        }
        start_s[g][NB] = a;
    }
    __syncthreads();
    if (node >= N) return;

    const unsigned short* hp = H + lane32 * 4;  // this lane's 4 channels
    float a0 = 0.f, a1 = 0.f, a2 = 0.f, a3 = 0.f;
    const int xcd = blockIdx.x & (NB - 1);

#pragma unroll
    for (int pp = 0; pp < NB; ++pp) {
        const int p = (xcd + pp) & (NB - 1);
        int k = start_s[g][p];
        const int k1 = start_s[g][p + 1];
        for (; k + 2 <= k1; k += 2) {
            int j0 = idx_s[g][k];
            int j1 = idx_s[g][k + 1];
            ushort4 v0 = *(const ushort4*)(hp + (size_t)j0 * C);
            ushort4 v1 = *(const ushort4*)(hp + (size_t)j1 * C);
            a0 += bf2f(v0.x);
            a1 += bf2f(v0.y);
            a2 += bf2f(v0.z);
            a3 += bf2f(v0.w);
            a0 += bf2f(v1.x);
            a1 += bf2f(v1.y);
            a2 += bf2f(v1.z);
            a3 += bf2f(v1.w);
        }
        if (k < k1) {
            int j0 = idx_s[g][k];
            ushort4 v0 = *(const ushort4*)(hp + (size_t)j0 * C);
            a0 += bf2f(v0.x);
            a1 += bf2f(v0.y);
            a2 += bf2f(v0.z);
            a3 += bf2f(v0.w);
        }
    }

    ushort4 sv = *(const ushort4*)(hp + (size_t)node * C);
    float s = invs[node];
    float r0 = (a0 + bf2f(sv.x)) * s;
    float r1 = (a1 + bf2f(sv.y)) * s;
    float r2 = (a2 + bf2f(sv.z)) * s;
    float r3 = (a3 + bf2f(sv.w)) * s;
    r0 = r0 > 0.f ? r0 : expm1f(r0);
    r1 = r1 > 0.f ? r1 : expm1f(r1);
    r2 = r2 > 0.f ? r2 : expm1f(r2);
    r3 = r3 > 0.f ? r3 : expm1f(r3);
    float4v rv = {r0, r1, r2, r3};
    *(float4v*)(out + (size_t)node * C + lane32 * 4) = rv;
}

// ---------------------------------------------------------------------------
// Fallback gather (round-11 proven, raw edge list) if ws can't hold sedge.
// ---------------------------------------------------------------------------
__global__ __launch_bounds__(256) void gather_elu_kernel(
    const unsigned short* __restrict__ H, const int* __restrict__ edge,
    const float* __restrict__ invs, float* __restrict__ out, int N) {
    __shared__ int idx_s[8][K];

    const int t = threadIdx.x;
    const int g = t >> 5;
    const int lane32 = t & 31;
    const int node = blockIdx.x * 8 + g;

    idx_s[g][lane32] = (node < N) ? edge[(size_t)node * K + lane32] : -1;
    __syncthreads();
    if (node >= N) return;

    const unsigned short* hp = H + lane32 * 4;
    float a0 = 0.f, a1 = 0.f, a2 = 0.f, a3 = 0.f;
#pragma unroll
    for (int k0 = 0; k0 < K; k0 += 16) {
        ushort4 v[16];
#pragma unroll
        for (int u = 0; u < 16; ++u) {
            int j = idx_s[g][k0 + u];
            j = (j < 0) ? N : j;
            v[u] = *(const ushort4*)(hp + (size_t)j * C);
        }
#pragma unroll
        for (int u = 0; u < 16; ++u) {
            a0 += bf2f(v[u].x);
            a1 += bf2f(v[u].y);
            a2 += bf2f(v[u].z);
            a3 += bf2f(v[u].w);
        }
    }
    ushort4 sv = *(const ushort4*)(hp + (size_t)node * C);
    float s = invs[node];
    float r0 = (a0 + bf2f(sv.x)) * s;
    float r1 = (a1 + bf2f(sv.y)) * s;
    float r2 = (a2 + bf2f(sv.z)) * s;
    float r3 = (a3 + bf2f(sv.w)) * s;
    r0 = r0 > 0.f ? r0 : expm1f(r0);
    r1 = r1 > 0.f ? r1 : expm1f(r1);
    r2 = r2 > 0.f ? r2 : expm1f(r2);
    r3 = r3 > 0.f ? r3 : expm1f(r3);
    float4v rv = {r0, r1, r2, r3};
    *(float4v*)(out + (size_t)node * C + lane32 * 4) = rv;
}

}  // namespace

extern "C" void kernel_launch(void* const* d_in, const int* in_sizes, int n_in,
                              void* d_out, int out_size, void* d_ws, size_t ws_size,
                              hipStream_t stream) {
    const float* x = (const float*)d_in[0];
    const int* edge = (const int*)d_in[1];
    const float* W1 = (const float*)d_in[2];
    const float* W2 = (const float*)d_in[3];
    float* out = (float*)d_out;
    const int N = in_sizes[0] / C;  // 100000

    char* ws = (char*)d_ws;
    const size_t invs_bytes = ((size_t)N * sizeof(float) + 255) & ~(size_t)255;
    const size_t h_bytes = (((size_t)(N + 1) * C * 2) + 255) & ~(size_t)255;
    const size_t whl_bytes = 2 * 2 * 16384 * sizeof(unsigned short);
    const size_t sedge_bytes = (((size_t)N * K * 4) + 255) & ~(size_t)255;
    const size_t offs_bytes = (size_t)N * 8;

    float* invs = (float*)ws;
    unsigned short* h1 = (unsigned short*)(ws + invs_bytes);
    unsigned short* whl = (unsigned short*)(ws + invs_bytes + h_bytes);

    const int prepBlocks = (N + 255) / 256;  // >= 129 (covers side jobs)
    const int gemmBlocks = (N + 127) / 128;
    const int gatherBlocks = (N + 7) / 8;

    const bool bucketed =
        ws_size >= invs_bytes + h_bytes + whl_bytes + sedge_bytes + offs_bytes;

    if (bucketed) {
        int* sedge = (int*)(ws + invs_bytes + h_bytes + whl_bytes);
        unsigned long long* offs =
            (unsigned long long*)(ws + invs_bytes + h_bytes + whl_bytes +
                                  sedge_bytes);

        prep_kernel<<<prepBlocks, 256, 0, stream>>>(
            edge, sedge, offs, invs, (unsigned int*)h1, W1, W2, whl, N, 1);
        // Layer 1: x -> h1 (bf16) -> act (fp32, in d_out)
        gemm_mfma_kernel<<<gemmBlocks, 256, 0, stream>>>(x, whl, invs, h1, N);
        gather_elu_b_kernel<<<gatherBlocks, 256, 0, stream>>>(h1, sedge, offs,
                                                              invs, out, N);
        // Layer 2: act (d_out) -> h1 (bf16) -> out
        gemm_mfma_kernel<<<gemmBlocks, 256, 0, stream>>>(out, whl + 32768, invs,
                                                         h1, N);
        gather_elu_b_kernel<<<gatherBlocks, 256, 0, stream>>>(h1, sedge, offs,
                                                              invs, out, N);
    } else {
        prep_kernel<<<prepBlocks, 256, 0, stream>>>(
            edge, nullptr, nullptr, invs, (unsigned int*)h1, W1, W2, whl, N, 0);
        gemm_mfma_kernel<<<gemmBlocks, 256, 0, stream>>>(x, whl, invs, h1, N);
        gather_elu_kernel<<<gatherBlocks, 256, 0, stream>>>(h1, edge, invs, out, N);
        gemm_mfma_kernel<<<gemmBlocks, 256, 0, stream>>>(out, whl + 32768, invs,
                                                         h1, N);
        gather_elu_kernel<<<gatherBlocks, 256, 0, stream>>>(h1, edge, invs, out, N);
    }
}

// Round 15
// 271.265 us; speedup vs baseline: 1.1124x; 1.1124x over previous
//
#include <hip/hip_runtime.h>
#include <hip/hip_bf16.h>
#include <math.h>

namespace {

constexpr int C = 128;  // channels
constexpr int K = 32;   // max degree

typedef float float4v __attribute__((ext_vector_type(4)));
typedef short short8v __attribute__((ext_vector_type(8)));  // 8 bf16 (4 VGPR)

__device__ __forceinline__ float bf2f(unsigned short u) {
    return __uint_as_float(((unsigned int)u) << 16);
}
__device__ __forceinline__ unsigned short f2bf(float x) {
    __hip_bfloat16 h = __float2bfloat16(x);
    return *(unsigned short*)&h;
}

// ---------------------------------------------------------------------------
// Kernel 0: invs[n] = 1/sqrt(1 + #valid neighbors). Block 0 also zeroes the
// padding row h[N][*] (the gathers' clamped-index target; h is reused for
// both layers, and GEMMs write only rows < N, so it stays zero).
// (round-10 proven verbatim)
// ---------------------------------------------------------------------------
__global__ __launch_bounds__(256) void deg_kernel(const int* __restrict__ edge,
                                                  float* __restrict__ invs,
                                                  unsigned int* __restrict__ hzero,
                                                  int N) {
    if (blockIdx.x == 0 && threadIdx.x < 64) {
        hzero[(size_t)N * (C / 2) + threadIdx.x] = 0u;  // row N: 128 bf16 zeros
    }
    int t = threadIdx.x;
    int node = blockIdx.x * 8 + (t >> 5);
    int k = t & 31;
    int e = (node < N) ? edge[(size_t)node * K + k] : -1;
    unsigned long long m = __ballot(e >= 0);
    int lane = t & 63;
    unsigned int half = (lane < 32) ? (unsigned int)(m & 0xffffffffULL)
                                    : (unsigned int)(m >> 32);
    int c = __popc(half);
    if (k == 0 && node < N) invs[node] = 1.0f / sqrtf((float)(c + 1));
}

// ---------------------------------------------------------------------------
// Kernel 1: H[n][ch] = bf16( (X[n] . W[ch]) * invs[n] ), X fp32 canonical.
// Split-bf16 MFMA GEMM, 3-term: x@W ~= xh@Wh + xl@Wh + xh@Wl (fp32-accurate).
// W split in-block into hi/lo bf16 LDS planes. (round-10 proven verbatim)
// ---------------------------------------------------------------------------
__global__ __launch_bounds__(256, 2) void gemm_mfma_kernel(
    const float* __restrict__ X, const float* __restrict__ W,
    const float* __restrict__ invs, unsigned short* __restrict__ H, int N) {
    __shared__ unsigned short Whl[2][C][136];

    const int t = threadIdx.x;
    const int n0 = blockIdx.x * 128;

    for (int p = t; p < C * C / 4; p += 256) {
        int row = p >> 5;
        int c4 = (p & 31) * 4;
        float4 w = ((const float4*)W)[p];
        float wv[4] = {w.x, w.y, w.z, w.w};
#pragma unroll
        for (int j = 0; j < 4; ++j) {
            unsigned short hb = f2bf(wv[j]);
            Whl[0][row][c4 + j] = hb;
            Whl[1][row][c4 + j] = f2bf(wv[j] - bf2f(hb));
        }
    }
    __syncthreads();

    const int wv = t >> 6;
    const int l = t & 63;
    const int lm = l & 15;
    const int lk = l >> 4;
    const int rbase = n0 + wv * 32;

    int rowA0 = rbase + lm;
    int rowA1 = rbase + 16 + lm;
    rowA0 = rowA0 < N ? rowA0 : N - 1;
    rowA1 = rowA1 < N ? rowA1 : N - 1;
    const float* xp0 = X + (size_t)rowA0 * C;
    const float* xp1 = X + (size_t)rowA1 * C;

    float4v acc[2][8];
#pragma unroll
    for (int rt = 0; rt < 2; ++rt)
#pragma unroll
        for (int ct = 0; ct < 8; ++ct) acc[rt][ct] = {0.f, 0.f, 0.f, 0.f};

#pragma unroll
    for (int ks = 0; ks < 4; ++ks) {
        const int kb = ks * 32 + lk * 8;
        float xr0[8], xr1[8];
        *(float4v*)&xr0[0] = *(const float4v*)(xp0 + kb);
        *(float4v*)&xr0[4] = *(const float4v*)(xp0 + kb + 4);
        *(float4v*)&xr1[0] = *(const float4v*)(xp1 + kb);
        *(float4v*)&xr1[4] = *(const float4v*)(xp1 + kb + 4);
        short8v ah0, al0, ah1, al1;
#pragma unroll
        for (int j = 0; j < 8; ++j) {
            unsigned short h0 = f2bf(xr0[j]);
            unsigned short h1 = f2bf(xr1[j]);
            ah0[j] = (short)h0;
            ah1[j] = (short)h1;
            al0[j] = (short)f2bf(xr0[j] - bf2f(h0));
            al1[j] = (short)f2bf(xr1[j] - bf2f(h1));
        }
#pragma unroll
        for (int ct = 0; ct < 8; ++ct) {
            short8v bh = *(const short8v*)&Whl[0][ct * 16 + lm][kb];
            short8v bl = *(const short8v*)&Whl[1][ct * 16 + lm][kb];
            acc[0][ct] = __builtin_amdgcn_mfma_f32_16x16x32_bf16(ah0, bh,
                                                                 acc[0][ct], 0, 0, 0);
            acc[0][ct] = __builtin_amdgcn_mfma_f32_16x16x32_bf16(al0, bh,
                                                                 acc[0][ct], 0, 0, 0);
            acc[0][ct] = __builtin_amdgcn_mfma_f32_16x16x32_bf16(ah0, bl,
                                                                 acc[0][ct], 0, 0, 0);
            acc[1][ct] = __builtin_amdgcn_mfma_f32_16x16x32_bf16(ah1, bh,
                                                                 acc[1][ct], 0, 0, 0);
            acc[1][ct] = __builtin_amdgcn_mfma_f32_16x16x32_bf16(al1, bh,
                                                                 acc[1][ct], 0, 0, 0);
            acc[1][ct] = __builtin_amdgcn_mfma_f32_16x16x32_bf16(ah1, bl,
                                                                 acc[1][ct], 0, 0, 0);
        }
    }

    float sc[2][4];
#pragma unroll
    for (int rt = 0; rt < 2; ++rt)
#pragma unroll
        for (int q = 0; q < 4; ++q) {
            int r = rbase + rt * 16 + lk * 4 + q;
            sc[rt][q] = invs[r < N ? r : N - 1];
        }
#pragma unroll
    for (int rt = 0; rt < 2; ++rt)
#pragma unroll
        for (int ct = 0; ct < 8; ++ct)
#pragma unroll
            for (int q = 0; q < 4; ++q) {
                int r = rbase + rt * 16 + lk * 4 + q;
                if (r < N)
                    H[(size_t)r * C + ct * 16 + lm] =
                        f2bf(acc[rt][ct][q] * sc[rt][q]);
            }
}

// ---------------------------------------------------------------------------
// Kernel 1b: layer-2 GEMM with EXACT-bf16 A (act from gather1): 2-term only
// (a@Wh + a@Wl — the A-residual is identically zero). A loads are ushort8
// (16 B) instead of 2x float4. Same tiling/epilogue as kernel 1.
// Numerics of the bf16-act chain validated rounds 12/13 (absmax unchanged).
// ---------------------------------------------------------------------------
__global__ __launch_bounds__(256, 2) void gemm_mfma_bf16a_kernel(
    const unsigned short* __restrict__ A, const float* __restrict__ W,
    const float* __restrict__ invs, unsigned short* __restrict__ H, int N) {
    __shared__ unsigned short Whl[2][C][136];

    const int t = threadIdx.x;
    const int n0 = blockIdx.x * 128;

    for (int p = t; p < C * C / 4; p += 256) {
        int row = p >> 5;
        int c4 = (p & 31) * 4;
        float4 w = ((const float4*)W)[p];
        float wv[4] = {w.x, w.y, w.z, w.w};
#pragma unroll
        for (int j = 0; j < 4; ++j) {
            unsigned short hb = f2bf(wv[j]);
            Whl[0][row][c4 + j] = hb;
            Whl[1][row][c4 + j] = f2bf(wv[j] - bf2f(hb));
        }
    }
    __syncthreads();

    const int wv = t >> 6;
    const int l = t & 63;
    const int lm = l & 15;
    const int lk = l >> 4;
    const int rbase = n0 + wv * 32;

    int rowA0 = rbase + lm;
    int rowA1 = rbase + 16 + lm;
    rowA0 = rowA0 < N ? rowA0 : N - 1;
    rowA1 = rowA1 < N ? rowA1 : N - 1;
    const unsigned short* ap0 = A + (size_t)rowA0 * C;
    const unsigned short* ap1 = A + (size_t)rowA1 * C;

    float4v acc[2][8];
#pragma unroll
    for (int rt = 0; rt < 2; ++rt)
#pragma unroll
        for (int ct = 0; ct < 8; ++ct) acc[rt][ct] = {0.f, 0.f, 0.f, 0.f};

#pragma unroll
    for (int ks = 0; ks < 4; ++ks) {
        const int kb = ks * 32 + lk * 8;
        short8v a0 = *(const short8v*)(ap0 + kb);
        short8v a1 = *(const short8v*)(ap1 + kb);
#pragma unroll
        for (int ct = 0; ct < 8; ++ct) {
            short8v bh = *(const short8v*)&Whl[0][ct * 16 + lm][kb];
            short8v bl = *(const short8v*)&Whl[1][ct * 16 + lm][kb];
            acc[0][ct] = __builtin_amdgcn_mfma_f32_16x16x32_bf16(a0, bh,
                                                                 acc[0][ct], 0, 0, 0);
            acc[0][ct] = __builtin_amdgcn_mfma_f32_16x16x32_bf16(a0, bl,
                                                                 acc[0][ct], 0, 0, 0);
            acc[1][ct] = __builtin_amdgcn_mfma_f32_16x16x32_bf16(a1, bh,
                                                                 acc[1][ct], 0, 0, 0);
            acc[1][ct] = __builtin_amdgcn_mfma_f32_16x16x32_bf16(a1, bl,
                                                                 acc[1][ct], 0, 0, 0);
        }
    }

    float sc[2][4];
#pragma unroll
    for (int rt = 0; rt < 2; ++rt)
#pragma unroll
        for (int q = 0; q < 4; ++q) {
            int r = rbase + rt * 16 + lk * 4 + q;
            sc[rt][q] = invs[r < N ? r : N - 1];
        }
#pragma unroll
    for (int rt = 0; rt < 2; ++rt)
#pragma unroll
        for (int ct = 0; ct < 8; ++ct)
#pragma unroll
            for (int q = 0; q < 4; ++q) {
                int r = rbase + rt * 16 + lk * 4 + q;
                if (r < N)
                    H[(size_t)r * C + ct * 16 + lm] =
                        f2bf(acc[rt][ct][q] * sc[rt][q]);
            }
}

// ---------------------------------------------------------------------------
// Kernel 2: canonical gather + ELU (round-10 proven, ~108 us, at the
// random-gather beyond-L2 wall: 6 structural variants converge 108-110 us).
// BF16OUT=1: store act as bf16 (layer-1 boundary; halves write traffic and
// feeds the 2-term gemm). BF16OUT=0: fp32 to d_out (final output).
// ---------------------------------------------------------------------------
template <int BF16OUT>
__global__ __launch_bounds__(256) void gather_elu_kernel(
    const unsigned short* __restrict__ H, const int* __restrict__ edge,
    const float* __restrict__ invs, void* __restrict__ outv, int N) {
    __shared__ int idx_s[8][K];

    const int t = threadIdx.x;
    const int g = t >> 5;
    const int lane32 = t & 31;
    const int node = blockIdx.x * 8 + g;

    idx_s[g][lane32] = (node < N) ? edge[(size_t)node * K + lane32] : -1;
    __syncthreads();
    if (node >= N) return;

    const unsigned short* hp = H + lane32 * 4;  // this lane's 4 channels
    float a0 = 0.f, a1 = 0.f, a2 = 0.f, a3 = 0.f;

#pragma unroll
    for (int k0 = 0; k0 < K; k0 += 16) {
        ushort4 v[16];
#pragma unroll
        for (int u = 0; u < 16; ++u) {
            int j = idx_s[g][k0 + u];
            j = (j < 0) ? N : j;  // row N is all zeros
            v[u] = *(const ushort4*)(hp + (size_t)j * C);
        }
#pragma unroll
        for (int u = 0; u < 16; ++u) {
            a0 += bf2f(v[u].x);
            a1 += bf2f(v[u].y);
            a2 += bf2f(v[u].z);
            a3 += bf2f(v[u].w);
        }
    }

    ushort4 sv = *(const ushort4*)(hp + (size_t)node * C);
    float s = invs[node];
    float r0 = (a0 + bf2f(sv.x)) * s;
    float r1 = (a1 + bf2f(sv.y)) * s;
    float r2 = (a2 + bf2f(sv.z)) * s;
    float r3 = (a3 + bf2f(sv.w)) * s;
    r0 = r0 > 0.f ? r0 : expm1f(r0);
    r1 = r1 > 0.f ? r1 : expm1f(r1);
    r2 = r2 > 0.f ? r2 : expm1f(r2);
    r3 = r3 > 0.f ? r3 : expm1f(r3);

    if (BF16OUT) {
        ushort4 rv;
        rv.x = f2bf(r0);
        rv.y = f2bf(r1);
        rv.z = f2bf(r2);
        rv.w = f2bf(r3);
        *(ushort4*)((unsigned short*)outv + (size_t)node * C + lane32 * 4) = rv;
    } else {
        float4v rv = {r0, r1, r2, r3};
        *(float4v*)((float*)outv + (size_t)node * C + lane32 * 4) = rv;
    }
}

}  // namespace

extern "C" void kernel_launch(void* const* d_in, const int* in_sizes, int n_in,
                              void* d_out, int out_size, void* d_ws, size_t ws_size,
                              hipStream_t stream) {
    const float* x = (const float*)d_in[0];
    const int* edge = (const int*)d_in[1];
    const float* W1 = (const float*)d_in[2];
    const float* W2 = (const float*)d_in[3];
    float* out = (float*)d_out;
    const int N = in_sizes[0] / C;  // 100000

    char* ws = (char*)d_ws;
    const size_t invs_bytes = ((size_t)N * sizeof(float) + 255) & ~(size_t)255;
    const size_t h_bytes = (((size_t)(N + 1) * C * 2) + 255) & ~(size_t)255;
    const size_t act_bytes = (((size_t)N * C * 2) + 255) & ~(size_t)255;

    float* invs = (float*)ws;
    unsigned short* h = (unsigned short*)(ws + invs_bytes);

    const int nodeBlocks = (N + 7) / 8;
    const int gemmBlocks = (N + 127) / 128;

    deg_kernel<<<nodeBlocks, 256, 0, stream>>>(edge, invs, (unsigned int*)h, N);
    // Layer 1: x -> h (bf16)
    gemm_mfma_kernel<<<gemmBlocks, 256, 0, stream>>>(x, W1, invs, h, N);

    if (ws_size >= invs_bytes + h_bytes + act_bytes) {
        // act stored bf16 (exact-bf16 A => 2-term layer-2 GEMM).
        unsigned short* act = (unsigned short*)(ws + invs_bytes + h_bytes);
        gather_elu_kernel<1><<<nodeBlocks, 256, 0, stream>>>(h, edge, invs, act, N);
        gemm_mfma_bf16a_kernel<<<gemmBlocks, 256, 0, stream>>>(act, W2, invs, h, N);
    } else {
        // Fallback (round-10 path): fp32 act in d_out, 3-term layer-2 GEMM.
        gather_elu_kernel<0><<<nodeBlocks, 256, 0, stream>>>(h, edge, invs, out, N);
        gemm_mfma_kernel<<<gemmBlocks, 256, 0, stream>>>(out, W2, invs, h, N);
    }
    // Layer 2 gather: h -> out (fp32)
    gather_elu_kernel<0><<<nodeBlocks, 256, 0, stream>>>(h, edge, invs, out, N);
}

// Round 16
// 268.482 us; speedup vs baseline: 1.1239x; 1.0104x over previous
//
#include <hip/hip_runtime.h>
#include <hip/hip_bf16.h>
#include <math.h>

namespace {

constexpr int C = 128;  // channels
constexpr int K = 32;   // max degree

typedef float float4v __attribute__((ext_vector_type(4)));
typedef short short8v __attribute__((ext_vector_type(8)));  // 8 bf16 (4 VGPR)

__device__ __forceinline__ float bf2f(unsigned short u) {
    return __uint_as_float(((unsigned int)u) << 16);
}
__device__ __forceinline__ unsigned short f2bf(float x) {
    __hip_bfloat16 h = __float2bfloat16(x);
    return *(unsigned short*)&h;
}

// ---------------------------------------------------------------------------
// Kernel 1: H[n][ch] = bf16( (X[n] . W[ch]) * invs[n] ), X fp32 canonical.
// Split-bf16 MFMA GEMM, 3-term: x@W ~= xh@Wh + xl@Wh + xh@Wl (fp32-accurate).
// invs computed INLINE (16 KB coalesced edge read/block + pair-shuffle) —
// the standalone deg kernel (~9 us + launch) is eliminated. Block 0 also
// zeroes h's padding row N (gathers' clamped-index target; stream-ordered
// before gather1; redone every call so graph-replay safe).
// ---------------------------------------------------------------------------
__global__ __launch_bounds__(256, 2) void gemm_mfma_kernel(
    const float* __restrict__ X, const float* __restrict__ W,
    const int* __restrict__ edge, unsigned short* __restrict__ H, int N) {
    __shared__ unsigned short Whl[2][C][136];
    __shared__ float invs_s[128];

    const int t = threadIdx.x;
    const int n0 = blockIdx.x * 128;

    if (blockIdx.x == 0 && t < 64) {
        ((unsigned int*)H)[(size_t)N * (C / 2) + t] = 0u;  // row N: zeros
    }

    // Inline invs for this block's 128 rows (2 threads/row).
    {
        const int r = t >> 1;
        const int hf = t & 1;
        const int n = n0 + r;
        int cnt = 0;
        if (n < N) {
            const int4* ep = (const int4*)(edge + (size_t)n * K + hf * 16);
#pragma unroll
            for (int q = 0; q < 4; ++q) {
                int4 e = ep[q];
                cnt += (e.x >= 0) + (e.y >= 0) + (e.z >= 0) + (e.w >= 0);
            }
        }
        cnt += __shfl_xor(cnt, 1);
        if (hf == 0) invs_s[r] = 1.0f / sqrtf((float)(cnt + 1));
    }

    for (int p = t; p < C * C / 4; p += 256) {
        int row = p >> 5;
        int c4 = (p & 31) * 4;
        float4 w = ((const float4*)W)[p];
        float wv[4] = {w.x, w.y, w.z, w.w};
#pragma unroll
        for (int j = 0; j < 4; ++j) {
            unsigned short hb = f2bf(wv[j]);
            Whl[0][row][c4 + j] = hb;
            Whl[1][row][c4 + j] = f2bf(wv[j] - bf2f(hb));
        }
    }
    __syncthreads();

    const int wv = t >> 6;
    const int l = t & 63;
    const int lm = l & 15;
    const int lk = l >> 4;
    const int rbase = n0 + wv * 32;

    int rowA0 = rbase + lm;
    int rowA1 = rbase + 16 + lm;
    rowA0 = rowA0 < N ? rowA0 : N - 1;
    rowA1 = rowA1 < N ? rowA1 : N - 1;
    const float* xp0 = X + (size_t)rowA0 * C;
    const float* xp1 = X + (size_t)rowA1 * C;

    float4v acc[2][8];
#pragma unroll
    for (int rt = 0; rt < 2; ++rt)
#pragma unroll
        for (int ct = 0; ct < 8; ++ct) acc[rt][ct] = {0.f, 0.f, 0.f, 0.f};

#pragma unroll
    for (int ks = 0; ks < 4; ++ks) {
        const int kb = ks * 32 + lk * 8;
        float xr0[8], xr1[8];
        *(float4v*)&xr0[0] = *(const float4v*)(xp0 + kb);
        *(float4v*)&xr0[4] = *(const float4v*)(xp0 + kb + 4);
        *(float4v*)&xr1[0] = *(const float4v*)(xp1 + kb);
        *(float4v*)&xr1[4] = *(const float4v*)(xp1 + kb + 4);
        short8v ah0, al0, ah1, al1;
#pragma unroll
        for (int j = 0; j < 8; ++j) {
            unsigned short h0 = f2bf(xr0[j]);
            unsigned short h1 = f2bf(xr1[j]);
            ah0[j] = (short)h0;
            ah1[j] = (short)h1;
            al0[j] = (short)f2bf(xr0[j] - bf2f(h0));
            al1[j] = (short)f2bf(xr1[j] - bf2f(h1));
        }
#pragma unroll
        for (int ct = 0; ct < 8; ++ct) {
            short8v bh = *(const short8v*)&Whl[0][ct * 16 + lm][kb];
            short8v bl = *(const short8v*)&Whl[1][ct * 16 + lm][kb];
            acc[0][ct] = __builtin_amdgcn_mfma_f32_16x16x32_bf16(ah0, bh,
                                                                 acc[0][ct], 0, 0, 0);
            acc[0][ct] = __builtin_amdgcn_mfma_f32_16x16x32_bf16(al0, bh,
                                                                 acc[0][ct], 0, 0, 0);
            acc[0][ct] = __builtin_amdgcn_mfma_f32_16x16x32_bf16(ah0, bl,
                                                                 acc[0][ct], 0, 0, 0);
            acc[1][ct] = __builtin_amdgcn_mfma_f32_16x16x32_bf16(ah1, bh,
                                                                 acc[1][ct], 0, 0, 0);
            acc[1][ct] = __builtin_amdgcn_mfma_f32_16x16x32_bf16(al1, bh,
                                                                 acc[1][ct], 0, 0, 0);
            acc[1][ct] = __builtin_amdgcn_mfma_f32_16x16x32_bf16(ah1, bl,
                                                                 acc[1][ct], 0, 0, 0);
        }
    }

#pragma unroll
    for (int rt = 0; rt < 2; ++rt)
#pragma unroll
        for (int ct = 0; ct < 8; ++ct)
#pragma unroll
            for (int q = 0; q < 4; ++q) {
                int r = rbase + rt * 16 + lk * 4 + q;
                if (r < N)
                    H[(size_t)r * C + ct * 16 + lm] =
                        f2bf(acc[rt][ct][q] * invs_s[r - n0]);
            }
}

// ---------------------------------------------------------------------------
// Kernel 1b: layer-2 GEMM, EXACT-bf16 A (act from gather1): 2-term MFMA.
// invs inline, same as kernel 1. (Numerics validated rounds 12-15.)
// ---------------------------------------------------------------------------
__global__ __launch_bounds__(256, 2) void gemm_mfma_bf16a_kernel(
    const unsigned short* __restrict__ A, const float* __restrict__ W,
    const int* __restrict__ edge, unsigned short* __restrict__ H, int N) {
    __shared__ unsigned short Whl[2][C][136];
    __shared__ float invs_s[128];

    const int t = threadIdx.x;
    const int n0 = blockIdx.x * 128;

    {
        const int r = t >> 1;
        const int hf = t & 1;
        const int n = n0 + r;
        int cnt = 0;
        if (n < N) {
            const int4* ep = (const int4*)(edge + (size_t)n * K + hf * 16);
#pragma unroll
            for (int q = 0; q < 4; ++q) {
                int4 e = ep[q];
                cnt += (e.x >= 0) + (e.y >= 0) + (e.z >= 0) + (e.w >= 0);
            }
        }
        cnt += __shfl_xor(cnt, 1);
        if (hf == 0) invs_s[r] = 1.0f / sqrtf((float)(cnt + 1));
    }

    for (int p = t; p < C * C / 4; p += 256) {
        int row = p >> 5;
        int c4 = (p & 31) * 4;
        float4 w = ((const float4*)W)[p];
        float wv[4] = {w.x, w.y, w.z, w.w};
#pragma unroll
        for (int j = 0; j < 4; ++j) {
            unsigned short hb = f2bf(wv[j]);
            Whl[0][row][c4 + j] = hb;
            Whl[1][row][c4 + j] = f2bf(wv[j] - bf2f(hb));
        }
    }
    __syncthreads();

    const int wv = t >> 6;
    const int l = t & 63;
    const int lm = l & 15;
    const int lk = l >> 4;
    const int rbase = n0 + wv * 32;

    int rowA0 = rbase + lm;
    int rowA1 = rbase + 16 + lm;
    rowA0 = rowA0 < N ? rowA0 : N - 1;
    rowA1 = rowA1 < N ? rowA1 : N - 1;
    const unsigned short* ap0 = A + (size_t)rowA0 * C;
    const unsigned short* ap1 = A + (size_t)rowA1 * C;

    float4v acc[2][8];
#pragma unroll
    for (int rt = 0; rt < 2; ++rt)
#pragma unroll
        for (int ct = 0; ct < 8; ++ct) acc[rt][ct] = {0.f, 0.f, 0.f, 0.f};

#pragma unroll
    for (int ks = 0; ks < 4; ++ks) {
        const int kb = ks * 32 + lk * 8;
        short8v a0 = *(const short8v*)(ap0 + kb);
        short8v a1 = *(const short8v*)(ap1 + kb);
#pragma unroll
        for (int ct = 0; ct < 8; ++ct) {
            short8v bh = *(const short8v*)&Whl[0][ct * 16 + lm][kb];
            short8v bl = *(const short8v*)&Whl[1][ct * 16 + lm][kb];
            acc[0][ct] = __builtin_amdgcn_mfma_f32_16x16x32_bf16(a0, bh,
                                                                 acc[0][ct], 0, 0, 0);
            acc[0][ct] = __builtin_amdgcn_mfma_f32_16x16x32_bf16(a0, bl,
                                                                 acc[0][ct], 0, 0, 0);
            acc[1][ct] = __builtin_amdgcn_mfma_f32_16x16x32_bf16(a1, bh,
                                                                 acc[1][ct], 0, 0, 0);
            acc[1][ct] = __builtin_amdgcn_mfma_f32_16x16x32_bf16(a1, bl,
                                                                 acc[1][ct], 0, 0, 0);
        }
    }

#pragma unroll
    for (int rt = 0; rt < 2; ++rt)
#pragma unroll
        for (int ct = 0; ct < 8; ++ct)
#pragma unroll
            for (int q = 0; q < 4; ++q) {
                int r = rbase + rt * 16 + lk * 4 + q;
                if (r < N)
                    H[(size_t)r * C + ct * 16 + lm] =
                        f2bf(acc[rt][ct][q] * invs_s[r - n0]);
            }
}

// ---------------------------------------------------------------------------
// Kernel 2: canonical gather + ELU (proven ~107 us, at the random-gather
// beyond-L2 wall). invs computed inline from the staged edge list (free
// ballot/popc — byte-identical math to the old deg kernel).
// BF16OUT=1: act bf16 (layer boundary). BF16OUT=0: fp32 to d_out.
// ---------------------------------------------------------------------------
template <int BF16OUT>
__global__ __launch_bounds__(256) void gather_elu_kernel(
    const unsigned short* __restrict__ H, const int* __restrict__ edge,
    void* __restrict__ outv, int N) {
    __shared__ int idx_s[8][K];
    __shared__ float invs_s[8];

    const int t = threadIdx.x;
    const int g = t >> 5;
    const int lane32 = t & 31;
    const int node = blockIdx.x * 8 + g;

    int e = (node < N) ? edge[(size_t)node * K + lane32] : -1;
    idx_s[g][lane32] = e;
    {
        unsigned long long m = __ballot(e >= 0);
        int lane = t & 63;
        unsigned int halfm = (lane < 32) ? (unsigned int)(m & 0xffffffffULL)
                                         : (unsigned int)(m >> 32);
        int cnt = __popc(halfm);
        if (lane32 == 0) invs_s[g] = 1.0f / sqrtf((float)(cnt + 1));
    }
    __syncthreads();
    if (node >= N) return;

    const unsigned short* hp = H + lane32 * 4;  // this lane's 4 channels
    float a0 = 0.f, a1 = 0.f, a2 = 0.f, a3 = 0.f;

#pragma unroll
    for (int k0 = 0; k0 < K; k0 += 16) {
        ushort4 v[16];
#pragma unroll
        for (int u = 0; u < 16; ++u) {
            int j = idx_s[g][k0 + u];
            j = (j < 0) ? N : j;  // row N is all zeros
            v[u] = *(const ushort4*)(hp + (size_t)j * C);
        }
#pragma unroll
        for (int u = 0; u < 16; ++u) {
            a0 += bf2f(v[u].x);
            a1 += bf2f(v[u].y);
            a2 += bf2f(v[u].z);
            a3 += bf2f(v[u].w);
        }
    }

    ushort4 sv = *(const ushort4*)(hp + (size_t)node * C);
    float s = invs_s[g];
    float r0 = (a0 + bf2f(sv.x)) * s;
    float r1 = (a1 + bf2f(sv.y)) * s;
    float r2 = (a2 + bf2f(sv.z)) * s;
    float r3 = (a3 + bf2f(sv.w)) * s;
    r0 = r0 > 0.f ? r0 : expm1f(r0);
    r1 = r1 > 0.f ? r1 : expm1f(r1);
    r2 = r2 > 0.f ? r2 : expm1f(r2);
    r3 = r3 > 0.f ? r3 : expm1f(r3);

    if (BF16OUT) {
        ushort4 rv;
        rv.x = f2bf(r0);
        rv.y = f2bf(r1);
        rv.z = f2bf(r2);
        rv.w = f2bf(r3);
        *(ushort4*)((unsigned short*)outv + (size_t)node * C + lane32 * 4) = rv;
    } else {
        float4v rv = {r0, r1, r2, r3};
        *(float4v*)((float*)outv + (size_t)node * C + lane32 * 4) = rv;
    }
}

}  // namespace

extern "C" void kernel_launch(void* const* d_in, const int* in_sizes, int n_in,
                              void* d_out, int out_size, void* d_ws, size_t ws_size,
                              hipStream_t stream) {
    const float* x = (const float*)d_in[0];
    const int* edge = (const int*)d_in[1];
    const float* W1 = (const float*)d_in[2];
    const float* W2 = (const float*)d_in[3];
    float* out = (float*)d_out;
    const int N = in_sizes[0] / C;  // 100000

    char* ws = (char*)d_ws;
    const size_t h_bytes = (((size_t)(N + 1) * C * 2) + 255) & ~(size_t)255;
    const size_t act_bytes = (((size_t)N * C * 2) + 255) & ~(size_t)255;

    unsigned short* h = (unsigned short*)ws;

    const int nodeBlocks = (N + 7) / 8;
    const int gemmBlocks = (N + 127) / 128;

    // Layer 1: x -> h (bf16); gemm1 zeroes h row N and computes invs inline.
    gemm_mfma_kernel<<<gemmBlocks, 256, 0, stream>>>(x, W1, edge, h, N);

    if (ws_size >= h_bytes + act_bytes) {
        // act stored bf16 (exact-bf16 A => 2-term layer-2 GEMM).
        unsigned short* act = (unsigned short*)(ws + h_bytes);
        gather_elu_kernel<1><<<nodeBlocks, 256, 0, stream>>>(h, edge, act, N);
        gemm_mfma_bf16a_kernel<<<gemmBlocks, 256, 0, stream>>>(act, W2, edge, h, N);
    } else {
        // Fallback: fp32 act in d_out, 3-term layer-2 GEMM.
        gather_elu_kernel<0><<<nodeBlocks, 256, 0, stream>>>(h, edge, out, N);
        gemm_mfma_kernel<<<gemmBlocks, 256, 0, stream>>>(out, W2, edge, h, N);
    }
    // Layer 2 gather: h -> out (fp32)
    gather_elu_kernel<0><<<nodeBlocks, 256, 0, stream>>>(h, edge, out, N);
}